// Round 1
// baseline (10696.265 us; speedup 1.0000x reference)
//
#include <hip/hip_runtime.h>
#include <stdint.h>

// Problem constants
#define BB   64
#define TT   512
#define HT   256
#define OO   128
#define GATES 1024   // 4*H

__device__ __forceinline__ float sigmoidf_(float x) {
    return 1.0f / (1.0f + __expf(-x));
}

// ---------------------------------------------------------------------------
// Embedding gather + decoder_action output
// grid: B*T blocks, 256 threads. Row = b*T+t.
__global__ __launch_bounds__(256) void embed_kernel(
    const int* __restrict__ actions, const float* __restrict__ emb_table,
    float* __restrict__ X, float* __restrict__ dact)
{
    int row = blockIdx.x;
    int t = row & (TT - 1);
    int id = (t == 0) ? 0 : actions[row - 1];
    X[(int64_t)row * HT + threadIdx.x] = emb_table[(int64_t)id * HT + threadIdx.x];
    if (threadIdx.x == 0) dact[row] = (float)actions[row];
}

// ---------------------------------------------------------------------------
// Transpose Whh[l] (4H x H row-major) -> WhT[l] (H x 4H): WhT[k][r] = Whh[r][k]
// grid: (1024, L), 256 threads
__global__ __launch_bounds__(256) void transpose_whh_kernel(
    const float* __restrict__ Whh, float* __restrict__ WhT)
{
    int l = blockIdx.y;
    int idx = blockIdx.x * 256 + threadIdx.x;   // 0..262143
    int k = idx >> 10;                          // 0..255
    int r = idx & 1023;                         // 0..1023
    WhT[(int64_t)l * (GATES * HT) + idx] = Whh[(int64_t)l * (GATES * HT) + (int64_t)r * HT + k];
}

// ---------------------------------------------------------------------------
// Generic fp32 tiled GEMM: C = act( A @ op(B) + bias1 + bias2 )
// A: [M,K] lda, row-major.  TRANS_B: B is [N,K] ldb (dot along k, "NT");
// else B is [K,N] ldb ("NN").  C: [M,N] ldc.  Batched via blockIdx.z strides.
// BM=BN=128, BK=16, 256 threads, 8x8 per thread. All dims assumed divisible.
template<bool TRANS_B, int ACT>
__global__ __launch_bounds__(256) void gemm128_kernel(
    const float* __restrict__ A, const float* __restrict__ Bm,
    float* __restrict__ C,
    int K, int lda, int ldb, int ldc,
    int64_t sA, int64_t sB, int64_t sC,
    const float* __restrict__ bias1, const float* __restrict__ bias2)
{
    constexpr int BM = 128, BN = 128, BK = 16;
    __shared__ __align__(16) float As[BK][BM + 4];
    __shared__ __align__(16) float Bs[BK][BN + 4];

    const int tid = threadIdx.x;
    const int m0 = blockIdx.y * BM;
    const int n0 = blockIdx.x * BN;
    A  += (int64_t)blockIdx.z * sA;
    Bm += (int64_t)blockIdx.z * sB;
    C  += (int64_t)blockIdx.z * sC;

    const int tm = tid & 15;    // row group
    const int tn = tid >> 4;    // col group

    float acc[8][8] = {};

    for (int k0 = 0; k0 < K; k0 += BK) {
        // --- load A tile (BM x BK), store transposed As[k][m]
        #pragma unroll
        for (int i = 0; i < 2; i++) {
            int idx = tid + i * 256;           // 0..511
            int ar = idx >> 2;                 // 0..127
            int ak = (idx & 3) * 4;            // 0,4,8,12
            const float4 v = *(const float4*)(A + (int64_t)(m0 + ar) * lda + k0 + ak);
            As[ak + 0][ar] = v.x; As[ak + 1][ar] = v.y;
            As[ak + 2][ar] = v.z; As[ak + 3][ar] = v.w;
        }
        // --- load B tile
        if (TRANS_B) {
            #pragma unroll
            for (int i = 0; i < 2; i++) {
                int idx = tid + i * 256;
                int br = idx >> 2;
                int bk = (idx & 3) * 4;
                const float4 v = *(const float4*)(Bm + (int64_t)(n0 + br) * ldb + k0 + bk);
                Bs[bk + 0][br] = v.x; Bs[bk + 1][br] = v.y;
                Bs[bk + 2][br] = v.z; Bs[bk + 3][br] = v.w;
            }
        } else {
            #pragma unroll
            for (int i = 0; i < 2; i++) {
                int idx = tid + i * 256;
                int bk = idx >> 5;             // 0..15
                int bn = (idx & 31) * 4;       // 0..124
                const float4 v = *(const float4*)(Bm + (int64_t)(k0 + bk) * ldb + n0 + bn);
                *(float4*)&Bs[bk][bn] = v;
            }
        }
        __syncthreads();

        #pragma unroll
        for (int k = 0; k < BK; k++) {
            float a[8], b[8];
            *(float4*)&a[0] = *(const float4*)&As[k][tm * 8];
            *(float4*)&a[4] = *(const float4*)&As[k][tm * 8 + 4];
            *(float4*)&b[0] = *(const float4*)&Bs[k][tn * 8];
            *(float4*)&b[4] = *(const float4*)&Bs[k][tn * 8 + 4];
            #pragma unroll
            for (int i = 0; i < 8; i++)
                #pragma unroll
                for (int j = 0; j < 8; j++)
                    acc[i][j] += a[i] * b[j];
        }
        __syncthreads();
    }

    // epilogue
    float bv[8];
    #pragma unroll
    for (int j = 0; j < 8; j++) {
        int n = n0 + tn * 8 + j;
        float b = 0.0f;
        if (bias1) b += bias1[n];
        if (bias2) b += bias2[n];
        bv[j] = b;
    }
    #pragma unroll
    for (int i = 0; i < 8; i++) {
        int64_t m = m0 + tm * 8 + i;
        float o[8];
        #pragma unroll
        for (int j = 0; j < 8; j++) {
            float v = acc[i][j] + bv[j];
            if (ACT == 1) v = tanhf(v);
            o[j] = v;
        }
        *(float4*)(C + m * ldc + n0 + tn * 8)     = make_float4(o[0], o[1], o[2], o[3]);
        *(float4*)(C + m * ldc + n0 + tn * 8 + 4) = make_float4(o[4], o[5], o[6], o[7]);
    }
}

// ---------------------------------------------------------------------------
// LSTM recurrence for one layer. grid: B blocks, 256 threads.
// Ag: precomputed x@Wih.T + bih + bhh, row (b*T+t), 1024 wide.
// WhT: transposed Whh, [256][1024].  X: output h, row stride ldx.
// Thread j owns gate rows 4j..4j+3 for the dot phase, hidden index j for state.
__global__ __launch_bounds__(256) void lstm_rec_kernel(
    const float* __restrict__ Ag, const float* __restrict__ WhT,
    const float* __restrict__ h0, const float* __restrict__ c0,
    float* __restrict__ X, int ldx)
{
    const int b = blockIdx.x;
    const int j = threadIdx.x;
    __shared__ __align__(16) float hsh[HT];
    __shared__ __align__(16) float gsh[GATES];

    float c = c0[b * HT + j];
    hsh[j] = h0[b * HT + j];
    __syncthreads();

    const float* Abase = Ag + (int64_t)b * TT * GATES;
    for (int t = 0; t < TT; t++) {
        float4 acc = *(const float4*)(Abase + (int64_t)t * GATES + j * 4);
        #pragma unroll 4
        for (int k = 0; k < HT; k += 4) {
            float4 h4 = *(const float4*)&hsh[k];
            float4 w0 = *(const float4*)(WhT + (k + 0) * GATES + j * 4);
            float4 w1 = *(const float4*)(WhT + (k + 1) * GATES + j * 4);
            float4 w2 = *(const float4*)(WhT + (k + 2) * GATES + j * 4);
            float4 w3 = *(const float4*)(WhT + (k + 3) * GATES + j * 4);
            acc.x += w0.x * h4.x + w1.x * h4.y + w2.x * h4.z + w3.x * h4.w;
            acc.y += w0.y * h4.x + w1.y * h4.y + w2.y * h4.z + w3.y * h4.w;
            acc.z += w0.z * h4.x + w1.z * h4.y + w2.z * h4.z + w3.z * h4.w;
            acc.w += w0.w * h4.x + w1.w * h4.y + w2.w * h4.z + w3.w * h4.w;
        }
        *(float4*)&gsh[j * 4] = acc;
        __syncthreads();                       // gate values visible
        float gi = gsh[j];
        float gf = gsh[HT + j];
        float gg = gsh[2 * HT + j];
        float go = gsh[3 * HT + j];
        c = sigmoidf_(gf) * c + sigmoidf_(gi) * tanhf(gg);
        float h = sigmoidf_(go) * tanhf(c);
        X[(int64_t)(b * TT + t) * ldx + j] = h;
        hsh[j] = h;                            // safe: all dots done (barrier above)
        __syncthreads();                       // h visible before next step
    }
}

// ---------------------------------------------------------------------------
// Softmax over rows of 512. One wave per row, 4 rows per block.
__global__ __launch_bounds__(256) void softmax512_kernel(float* __restrict__ S)
{
    int row = blockIdx.x * 4 + (threadIdx.x >> 6);
    int lane = threadIdx.x & 63;
    float* p = S + (int64_t)row * 512 + lane * 8;
    float4 v0 = *(float4*)p;
    float4 v1 = *(float4*)(p + 4);
    float m = fmaxf(fmaxf(fmaxf(v0.x, v0.y), fmaxf(v0.z, v0.w)),
                    fmaxf(fmaxf(v1.x, v1.y), fmaxf(v1.z, v1.w)));
    #pragma unroll
    for (int off = 32; off; off >>= 1) m = fmaxf(m, __shfl_xor(m, off));
    v0.x = __expf(v0.x - m); v0.y = __expf(v0.y - m);
    v0.z = __expf(v0.z - m); v0.w = __expf(v0.w - m);
    v1.x = __expf(v1.x - m); v1.y = __expf(v1.y - m);
    v1.z = __expf(v1.z - m); v1.w = __expf(v1.w - m);
    float s = v0.x + v0.y + v0.z + v0.w + v1.x + v1.y + v1.z + v1.w;
    #pragma unroll
    for (int off = 32; off; off >>= 1) s += __shfl_xor(s, off);
    float inv = 1.0f / s;
    v0.x *= inv; v0.y *= inv; v0.z *= inv; v0.w *= inv;
    v1.x *= inv; v1.y *= inv; v1.z *= inv; v1.w *= inv;
    *(float4*)p = v0;
    *(float4*)(p + 4) = v1;
}

// ---------------------------------------------------------------------------
// values[m] = dot(qvalues[m,:], logits[m,:]) over O=128. One wave per row.
__global__ __launch_bounds__(256) void values_kernel(
    const float* __restrict__ Q, const float* __restrict__ L, float* __restrict__ V)
{
    int row = blockIdx.x * 4 + (threadIdx.x >> 6);
    int lane = threadIdx.x & 63;
    float2 q = *(const float2*)(Q + (int64_t)row * OO + lane * 2);
    float2 l = *(const float2*)(L + (int64_t)row * OO + lane * 2);
    float s = q.x * l.x + q.y * l.y;
    #pragma unroll
    for (int off = 32; off; off >>= 1) s += __shfl_xor(s, off);
    if (lane == 0) V[row] = s;
}

// ---------------------------------------------------------------------------
extern "C" void kernel_launch(void* const* d_in, const int* in_sizes, int n_in,
                              void* d_out, int out_size, void* d_ws, size_t ws_size,
                              hipStream_t stream)
{
    const float* enc      = (const float*)d_in[0];   // [B,T,H]
    const float* h0       = (const float*)d_in[1];   // [L,B,H]
    const float* c0       = (const float*)d_in[2];
    const int*   actions  = (const int*)  d_in[3];   // [B,T]
    const float* emb_t    = (const float*)d_in[4];   // [O,H]
    const float* Wih      = (const float*)d_in[5];   // [L,4H,H]
    const float* Whh      = (const float*)d_in[6];   // [L,4H,H]
    const float* bih      = (const float*)d_in[7];   // [L,4H]
    const float* bhh      = (const float*)d_in[8];
    const float* W_attn   = (const float*)d_in[9];   // [H,H]
    const float* b_attn   = (const float*)d_in[10];  // [H]
    const float* W_concat = (const float*)d_in[11];  // [H,2H]
    const float* b_concat = (const float*)d_in[12];  // [H]
    const float* W_out    = (const float*)d_in[13];  // [O,H]
    const float* W_critic = (const float*)d_in[14];  // [O,O]
    const float* b_critic = (const float*)d_in[15];  // [O]
    (void)in_sizes; (void)n_in; (void)out_size; (void)ws_size;

    const int M = BB * TT;                 // 32768 rows

    float* out    = (float*)d_out;
    float* dact   = out;                   // [B*T]
    float* logits = out + M;               // [B*T, O]
    float* values = out + M + (int64_t)M * OO;

    // Workspace arena (floats). Total = 67,108,864 floats = 256 MiB.
    //   gates : 33,554,432  (A pre-activations; later reused for scores, then qv)
    //   xbuf  :  8,388,608  (emb -> X1 -> dec)
    //   cat   : 16,777,216  ([out | ctx], row stride 512)
    //   keys  :  8,388,608  (WhT overlaid here before keys are computed)
    float* ws    = (float*)d_ws;
    float* gates = ws;
    float* xbuf  = ws + 33554432;
    float* cat   = ws + 41943040;
    float* keys  = ws + 58720256;
    float* WhT   = keys;     // dead before keys GEMM runs
    float* scores = gates;   // gates dead after layer-1 recurrence
    float* qv     = gates;   // scores dead after ctx GEMM
    float* dec    = xbuf;    // X1 dead after layer-1 input GEMM

    const int64_t LW = (int64_t)GATES * HT;   // 262144, per-layer weight elems

    // 1) embedding + decoder_action
    hipLaunchKernelGGL(embed_kernel, dim3(M), dim3(256), 0, stream,
                       actions, emb_t, xbuf, dact);
    // 2) transpose Whh for both layers
    hipLaunchKernelGGL(transpose_whh_kernel, dim3(1024, 2), dim3(256), 0, stream,
                       Whh, WhT);
    // 3) layer-0 input GEMM: gates = emb @ Wih0^T + bih0 + bhh0
    hipLaunchKernelGGL((gemm128_kernel<true, 0>), dim3(8, 256, 1), dim3(256), 0, stream,
                       xbuf, Wih, gates, HT, HT, HT, GATES,
                       (int64_t)0, (int64_t)0, (int64_t)0, bih, bhh);
    // 4) layer-0 recurrence -> X1 (xbuf, ldx=256)
    hipLaunchKernelGGL(lstm_rec_kernel, dim3(BB), dim3(256), 0, stream,
                       gates, WhT, h0, c0, xbuf, HT);
    // 5) layer-1 input GEMM: gates = X1 @ Wih1^T + bih1 + bhh1
    hipLaunchKernelGGL((gemm128_kernel<true, 0>), dim3(8, 256, 1), dim3(256), 0, stream,
                       xbuf, Wih + LW, gates, HT, HT, HT, GATES,
                       (int64_t)0, (int64_t)0, (int64_t)0, bih + GATES, bhh + GATES);
    // 6) layer-1 recurrence -> cat[:, 0:256] (ldx=512)
    hipLaunchKernelGGL(lstm_rec_kernel, dim3(BB), dim3(256), 0, stream,
                       gates, WhT + LW, h0 + BB * HT, c0 + BB * HT, cat, 2 * HT);
    // 7) keys = enc @ W_attn^T + b_attn
    hipLaunchKernelGGL((gemm128_kernel<true, 0>), dim3(2, 256, 1), dim3(256), 0, stream,
                       enc, W_attn, keys, HT, HT, HT, HT,
                       (int64_t)0, (int64_t)0, (int64_t)0, b_attn, (const float*)nullptr);
    // 8) scores[b] = out[b] @ keys[b]^T   (batched NT, M=N=512, K=256)
    hipLaunchKernelGGL((gemm128_kernel<true, 0>), dim3(4, 4, BB), dim3(256), 0, stream,
                       cat, keys, scores, HT, 2 * HT, HT, TT,
                       (int64_t)TT * 2 * HT, (int64_t)TT * HT, (int64_t)TT * TT,
                       (const float*)nullptr, (const float*)nullptr);
    // 9) softmax over s
    hipLaunchKernelGGL(softmax512_kernel, dim3(M / 4), dim3(256), 0, stream, scores);
    // 10) ctx[b] = P[b] @ enc[b]   (batched NN, M=512, N=256, K=512) -> cat[:,256:]
    hipLaunchKernelGGL((gemm128_kernel<false, 0>), dim3(2, 4, BB), dim3(256), 0, stream,
                       scores, enc, cat + HT, TT, TT, HT, 2 * HT,
                       (int64_t)TT * TT, (int64_t)TT * HT, (int64_t)TT * 2 * HT,
                       (const float*)nullptr, (const float*)nullptr);
    // 11) dec = tanh(cat @ W_concat^T + b_concat)  (K=512)
    hipLaunchKernelGGL((gemm128_kernel<true, 1>), dim3(2, 256, 1), dim3(256), 0, stream,
                       cat, W_concat, dec, 2 * HT, 2 * HT, 2 * HT, HT,
                       (int64_t)0, (int64_t)0, (int64_t)0, b_concat, (const float*)nullptr);
    // 12) logits = dec @ W_out^T  -> d_out
    hipLaunchKernelGGL((gemm128_kernel<true, 0>), dim3(1, 256, 1), dim3(256), 0, stream,
                       dec, W_out, logits, HT, HT, HT, OO,
                       (int64_t)0, (int64_t)0, (int64_t)0,
                       (const float*)nullptr, (const float*)nullptr);
    // 13) qv = logits @ W_critic^T + b_critic  (K=128)
    hipLaunchKernelGGL((gemm128_kernel<true, 0>), dim3(1, 256, 1), dim3(256), 0, stream,
                       logits, W_critic, qv, OO, OO, OO, OO,
                       (int64_t)0, (int64_t)0, (int64_t)0, b_critic, (const float*)nullptr);
    // 14) values[m] = dot(qv[m], logits[m])
    hipLaunchKernelGGL(values_kernel, dim3(M / 4), dim3(256), 0, stream,
                       qv, logits, values);
}